// Round 11
// baseline (209.637 us; speedup 1.0000x reference)
//
#include <hip/hip_runtime.h>

#define NL 7
#define NA 32
#define PERL 528
#define NF 3696
#define RSH 24                   // halves per staged row (48 B stride, 16B-aligned)
#define SQRT2f 1.41421356237309515f

typedef short bf16x8 __attribute__((ext_vector_type(8)));
typedef float f32x16 __attribute__((ext_vector_type(16)));
typedef unsigned uint4v __attribute__((ext_vector_type(4)));
typedef float f32x4u __attribute__((ext_vector_type(4), aligned(4)));

__device__ __forceinline__ unsigned cvtpk(float lo, float hi) {
    unsigned r;
    asm("v_cvt_pk_bf16_f32 %0, %1, %2" : "=v"(r) : "v"(lo), "v"(hi));
    return r;
}

// Wave w fully owns l = L: stage 32 rows (2 lanes/row: halves h=0/1),
// then read its own fragment and do ONE 32x32x16 MFMA. No cross-wave deps.
template<int L>
__device__ __forceinline__ f32x16 process(const float* __restrict__ se, int j,
                                          int lane, unsigned short* __restrict__ Th) {
    constexpr int m21 = 2 * L + 1;
    const int a = lane & 31;
    const int h = lane >> 5;
    const float* rowp = se + (size_t)j * (32 * m21) + a * m21;

    unsigned pk[4] = {0u, 0u, 0u, 0u};
    if (h == 0) {
        float v[8];
        #pragma unroll
        for (int i = 0; i < 8; ++i) v[i] = 0.0f;
        if constexpr (m21 >= 8) {
            f32x4u t0 = *(const f32x4u*)rowp;
            f32x4u t1 = *(const f32x4u*)(rowp + 4);
            #pragma unroll
            for (int i = 0; i < 4; ++i) { v[i] = t0[i]; v[4 + i] = t1[i]; }
        } else if constexpr (m21 == 1) {
            v[0] = rowp[0];
        } else if constexpr (m21 == 3) {
            f32x4u t = *(const f32x4u*)rowp;             // 1-elem overread into next row (safe)
            v[0] = t[0]; v[1] = t[1]; v[2] = t[2];
        } else if constexpr (m21 == 5) {
            f32x4u t = *(const f32x4u*)rowp;
            v[0] = t[0]; v[1] = t[1]; v[2] = t[2]; v[3] = t[3];
            v[4] = rowp[4];
        } else {                                         // m21 == 7, overlap, no overread
            f32x4u t0 = *(const f32x4u*)rowp;
            f32x4u t1 = *(const f32x4u*)(rowp + 3);
            v[0] = t0[0]; v[1] = t0[1]; v[2] = t0[2];
            v[3] = t1[0]; v[4] = t1[1]; v[5] = t1[2]; v[6] = t1[3];
        }
        #pragma unroll
        for (int p = 0; p < 4; ++p)
            if (2 * p < m21) pk[p] = cvtpk(v[2 * p], v[2 * p + 1]);
    } else if constexpr (m21 > 8) {                      // tail m = 8..m21-1
        float v[8];
        #pragma unroll
        for (int i = 0; i < 8; ++i) v[i] = 0.0f;
        if constexpr (m21 == 9) {
            v[0] = rowp[8];
        } else if constexpr (m21 == 11) {
            f32x4u t = *(const f32x4u*)(rowp + 7);       // elems 7..10, overlap
            v[0] = t[1]; v[1] = t[2]; v[2] = t[3];
        } else {                                         // m21 == 13
            f32x4u t = *(const f32x4u*)(rowp + 8);
            v[0] = t[0]; v[1] = t[1]; v[2] = t[2]; v[3] = t[3];
            v[4] = rowp[12];
        }
        #pragma unroll
        for (int p = 0; p < 4; ++p)
            if (8 + 2 * p < m21) pk[p] = cvtpk(v[2 * p], v[2 * p + 1]);
    }
    unsigned short* rp = Th + (L * 32 + a) * RSH + 8 * h;
    *(uint4*)rp = make_uint4(pk[0], pk[1], pk[2], pk[3]);

    // intra-wave LDS RAW only: DS ops are in-order per wave; fence the compiler.
    __builtin_amdgcn_wave_barrier();
    asm volatile("" ::: "memory");

    const bf16x8 f = *(const bf16x8*)(Th + (L * 32 + (lane & 31)) * RSH + (lane >> 5) * 8);
    f32x16 z;
    #pragma unroll
    for (int r = 0; r < 16; ++r) z[r] = 0.0f;
    return __builtin_amdgcn_mfma_f32_32x32x16_bf16(f, f, z, 0, 0, 0);
}

__global__ __launch_bounds__(512, 8) void ps_kernel(
    const float* __restrict__ se0, const float* __restrict__ se1,
    const float* __restrict__ se2, const float* __restrict__ se3,
    const float* __restrict__ se4, const float* __restrict__ se5,
    const float* __restrict__ se6, float* __restrict__ out)
{
    __shared__ __align__(16) float LB[NF];   // staged bf16 rows (10752 B), then output buffer
    __shared__ float s_wsum[8];
    unsigned short* Th = (unsigned short*)LB;

    const int j    = blockIdx.x;
    const int tid  = threadIdx.x;
    const int wv   = tid >> 6;
    const int lane = tid & 63;

    // ---- phase 1+2: wave-local stage + MFMA (wave w owns l = w; wave 7 idle) ----
    f32x16 acc;
    #pragma unroll
    for (int r = 0; r < 16; ++r) acc[r] = 0.0f;
    switch (wv) {
        case 0: acc = process<0>(se0, j, lane, Th); break;
        case 1: acc = process<1>(se1, j, lane, Th); break;
        case 2: acc = process<2>(se2, j, lane, Th); break;
        case 3: acc = process<3>(se3, j, lane, Th); break;
        case 4: acc = process<4>(se4, j, lane, Th); break;
        case 5: acc = process<5>(se5, j, lane, Th); break;
        case 6: acc = process<6>(se6, j, lane, Th); break;
        default: break;
    }

    // ---- phase 3: ssq with exact 1/(2l+1) weight (wave 7 contributes 0) ----
    const float rs = rsqrtf((float)(2 * wv + 1));
    float ssq = 0.0f;
    #pragma unroll
    for (int r = 0; r < 16; ++r) ssq += acc[r] * acc[r];
    ssq *= rs * rs;

    #pragma unroll
    for (int off = 32; off >= 1; off >>= 1) ssq += __shfl_down(ssq, off, 64);
    if (lane == 0) s_wsum[wv] = ssq;
    __syncthreads();   // B1: all frag reads done, wsum ready

    float tot = 0.0f;
    #pragma unroll
    for (int w = 0; w < 8; ++w) tot += s_wsum[w];
    const float inv = 1.0f / fmaxf(sqrtf(tot), 1e-12f);

    // ---- phase 4: scatter with rs*inv*(sqrt2) folded; reuses LB as output buffer ----
    // C layout: col = lane&31, row = (r&3)+8*(r>>2)+4*(lane>>5). G symmetric ->
    // lane owns OUTPUT row c, columns rw; upper offset = ubase + rw.
    if (wv < NL) {
        const int c     = lane & 31;
        const int hi4   = (lane >> 5) * 4;
        const int ubase = 32 + (c * (63 - c)) / 2 - c - 1;
        const float dsc = rs * inv, usc = dsc * SQRT2f;
        float* ol = LB + wv * PERL;
        #pragma unroll
        for (int r = 0; r < 16; ++r) {
            const int rw = (r & 3) + 8 * (r >> 2) + hi4;
            if (rw >= c) {
                const bool d = (rw == c);
                ol[d ? c : (ubase + rw)] = acc[r] * (d ? dsc : usc);
            }
        }
    }
    __syncthreads();   // B2

    // ---- phase 5: pure coalesced nontemporal copy (values already normalized) ----
    const uint4v* ob4 = (const uint4v*)LB;
    uint4v* op4 = (uint4v*)(out + (size_t)j * NF);
    #pragma unroll
    for (int k = 0; k < 2; ++k) {
        const int q = tid + k * 512;
        if (q < 924) {
            uint4v v = ob4[q];
            __builtin_nontemporal_store(v, &op4[q]);
        }
    }
}

extern "C" void kernel_launch(void* const* d_in, const int* in_sizes, int n_in,
                              void* d_out, int out_size, void* d_ws, size_t ws_size,
                              hipStream_t stream) {
    const float* se0 = (const float*)d_in[0];
    const float* se1 = (const float*)d_in[1];
    const float* se2 = (const float*)d_in[2];
    const float* se3 = (const float*)d_in[3];
    const float* se4 = (const float*)d_in[4];
    const float* se5 = (const float*)d_in[5];
    const float* se6 = (const float*)d_in[6];
    float* out = (float*)d_out;

    const int J = in_sizes[0] / NA;   // se_0 is (J, 32, 1)
    ps_kernel<<<J, 512, 0, stream>>>(se0, se1, se2, se3, se4, se5, se6, out);
}